// Round 1
// baseline (406.780 us; speedup 1.0000x reference)
//
#include <hip/hip_runtime.h>
#include <hip/hip_bf16.h>

#define N_NODES 50000
#define N_EDGES 800000
#define CAP 128

typedef __attribute__((ext_vector_type(8))) short bf16x8;
typedef __attribute__((ext_vector_type(4))) float f32x4;

// ws layout (bytes):
// cnt4:   [N][4] int        @ 0           800000
// cursor: [N] int           @ 800000      200000
// ebuf:   [N][CAP] int      @ 1000000     25600000
// x2:     [N][256] bf16     @ 26600000    25600000
// qkv:    [3][N][256] bf16  @ 52200000    76800000
// WT:     [1024][256] bf16  @ 129000000   524288
// bias:   [1024] f32        @ 129524288   4096

__global__ __launch_bounds__(256) void prep_wt(
    const float* __restrict__ Wq, const float* __restrict__ bq,
    const float* __restrict__ Wk, const float* __restrict__ bk,
    const float* __restrict__ Wv, const float* __restrict__ bv,
    const float* __restrict__ Ws, const float* __restrict__ bs,
    __hip_bfloat16* __restrict__ WT, float* __restrict__ bias)
{
    int tid = blockIdx.x * blockDim.x + threadIdx.x;  // 0..32767
    int ng = tid & 1023;          // output row of WT (n-major over q|k|v|s)
    int kc = tid >> 10;           // 0..31, chunk of 8 k's
    int m = ng >> 8;
    int col = ng & 255;
    const float* W = (m == 0) ? Wq : (m == 1) ? Wk : (m == 2) ? Wv : Ws;
    __align__(16) __hip_bfloat16 tmp[8];
    for (int j = 0; j < 8; ++j)
        tmp[j] = __float2bfloat16(W[(kc * 8 + j) * 256 + col]);
    *(bf16x8*)((ushort*)WT + (size_t)ng * 256 + kc * 8) = *(bf16x8*)tmp;
    if (kc == 0) {
        const float* b = (m == 0) ? bq : (m == 1) ? bk : (m == 2) ? bv : bs;
        bias[ng] = b[col];
    }
}

__global__ __launch_bounds__(256) void count_scatter(
    const int* __restrict__ ei, const int* __restrict__ et,
    int* __restrict__ cnt4, int* __restrict__ cursor, int* __restrict__ ebuf)
{
    int e = blockIdx.x * blockDim.x + threadIdx.x;
    if (e >= N_EDGES) return;
    int s = ei[e];
    int d = ei[N_EDGES + e];
    int t = et[e];
    atomicAdd(&cnt4[s * 4 + t], 1);
    int pos = atomicAdd(&cursor[d], 1);
    if (pos < CAP) ebuf[d * CAP + pos] = s;
}

__global__ __launch_bounds__(256) void node_feat(
    const float* __restrict__ x, const float* __restrict__ emb,
    const int* __restrict__ cnt4, __hip_bfloat16* __restrict__ x2)
{
    int n = blockIdx.x;
    int c = threadIdx.x;
    int c0 = cnt4[n * 4 + 0], c1 = cnt4[n * 4 + 1];
    int c2 = cnt4[n * 4 + 2], c3 = cnt4[n * 4 + 3];
    float cnt = (float)(c0 + c1 + c2 + c3);
    float inv = 1.0f / fmaxf(cnt, 1.0f);
    float v = x[(size_t)n * 256 + c] +
              (c0 * emb[c] + c1 * emb[256 + c] + c2 * emb[512 + c] + c3 * emb[768 + c]) * inv;
    x2[(size_t)n * 256 + c] = __float2bfloat16(v);
}

__global__ __launch_bounds__(256) void gemm_qkvs(
    const __hip_bfloat16* __restrict__ x2, const __hip_bfloat16* __restrict__ WT,
    const float* __restrict__ bias,
    __hip_bfloat16* __restrict__ qkv, float* __restrict__ out)
{
    __shared__ __align__(16) ushort As[128][40];
    __shared__ __align__(16) ushort Bs[128][40];
    int m0 = blockIdx.x * 128;
    int n0 = blockIdx.y * 128;
    int tid = threadIdx.x;
    int lane = tid & 63, w = tid >> 6;
    int wm = w >> 1, wn = w & 1;
    f32x4 acc[4][4] = {};

    const ushort* xp = (const ushort*)x2;
    const ushort* wp = (const ushort*)WT;

    for (int kt = 0; kt < 256; kt += 32) {
        for (int it = 0; it < 2; ++it) {
            int idx = tid + it * 256;            // 0..511
            int row = idx >> 2, ch = (idx & 3) * 8;
            int ar = m0 + row; if (ar >= N_NODES) ar = N_NODES - 1;
            *(bf16x8*)&As[row][ch] = *(const bf16x8*)(xp + (size_t)ar * 256 + kt + ch);
            *(bf16x8*)&Bs[row][ch] = *(const bf16x8*)(wp + (size_t)(n0 + row) * 256 + kt + ch);
        }
        __syncthreads();
        int r = lane & 15, kq = (lane >> 4) * 8;
        bf16x8 af[4], bfr[4];
        for (int mi = 0; mi < 4; ++mi) af[mi]  = *(bf16x8*)&As[wm * 64 + mi * 16 + r][kq];
        for (int ni = 0; ni < 4; ++ni) bfr[ni] = *(bf16x8*)&Bs[wn * 64 + ni * 16 + r][kq];
        for (int mi = 0; mi < 4; ++mi)
            for (int ni = 0; ni < 4; ++ni)
                acc[mi][ni] = __builtin_amdgcn_mfma_f32_16x16x32_bf16(
                    af[mi], bfr[ni], acc[mi][ni], 0, 0, 0);
        __syncthreads();
    }

    int r = lane & 15, rg = (lane >> 4) * 4;
    int mtx = n0 >> 8;  // 0=q 1=k 2=v 3=s (uniform per block since BN=128)
    for (int mi = 0; mi < 4; ++mi) {
        int rowb = m0 + wm * 64 + mi * 16 + rg;
        for (int ni = 0; ni < 4; ++ni) {
            int gcol = n0 + wn * 64 + ni * 16 + r;
            float b = bias[gcol];
            int col = gcol & 255;
            for (int rr = 0; rr < 4; ++rr) {
                int row = rowb + rr;
                if (row < N_NODES) {
                    float v = acc[mi][ni][rr] + b;
                    if (mtx == 3) out[(size_t)row * 256 + col] = v;
                    else ((__hip_bfloat16*)qkv)[(size_t)mtx * N_NODES * 256 +
                                                (size_t)row * 256 + col] = __float2bfloat16(v);
                }
            }
        }
    }
}

__global__ __launch_bounds__(256) void attn(
    const __hip_bfloat16* __restrict__ qkv,
    const int* __restrict__ cursor, const int* __restrict__ ebuf,
    float* __restrict__ out)
{
    int wid = (blockIdx.x * blockDim.x + threadIdx.x) >> 6;
    int lane = threadIdx.x & 63;
    if (wid >= N_NODES) return;
    int n = wid;
    const __hip_bfloat16* qb = qkv;
    const __hip_bfloat16* kb = qkv + (size_t)N_NODES * 256;
    const __hip_bfloat16* vb = qkv + (size_t)2 * N_NODES * 256;
    float qf[4];
    for (int h = 0; h < 4; ++h) qf[h] = __bfloat162float(qb[(size_t)n * 256 + h * 64 + lane]);
    int deg = cursor[n]; if (deg > CAP) deg = CAP;
    int s0 = 0, s1 = 0;
    if (lane < deg) s0 = ebuf[n * CAP + lane];
    if (lane + 64 < deg) s1 = ebuf[n * CAP + 64 + lane];
    float m[4], l[4], acc[4];
    for (int h = 0; h < 4; ++h) { m[h] = -1e30f; l[h] = 0.f; acc[h] = 0.f; }
    for (int i = 0; i < deg; ++i) {
        int src = __shfl(i < 64 ? s0 : s1, i & 63);
        float p[4], vf[4];
        for (int h = 0; h < 4; ++h) {
            float kf = __bfloat162float(kb[(size_t)src * 256 + h * 64 + lane]);
            p[h] = qf[h] * kf;
            vf[h] = __bfloat162float(vb[(size_t)src * 256 + h * 64 + lane]);
        }
        for (int d = 1; d < 64; d <<= 1)
            for (int h = 0; h < 4; ++h) p[h] += __shfl_xor(p[h], d);
        for (int h = 0; h < 4; ++h) {
            float alpha = p[h] * 0.125f;     // 1/sqrt(64)
            float mn = fmaxf(m[h], alpha);
            float sc = __expf(m[h] - mn);
            float wgt = __expf(alpha - mn);
            l[h] = l[h] * sc + wgt;
            acc[h] = acc[h] * sc + wgt * vf[h];
            m[h] = mn;
        }
    }
    for (int h = 0; h < 4; ++h) {
        float o = acc[h] / (l[h] + 1e-16f);
        out[(size_t)n * 256 + h * 64 + lane] += o;
    }
}

extern "C" void kernel_launch(void* const* d_in, const int* in_sizes, int n_in,
                              void* d_out, int out_size, void* d_ws, size_t ws_size,
                              hipStream_t stream)
{
    const float* x   = (const float*)d_in[0];
    const int*   ei  = (const int*)d_in[1];
    const int*   et  = (const int*)d_in[2];
    const float* emb = (const float*)d_in[3];
    const float* Wq  = (const float*)d_in[4];
    const float* bq  = (const float*)d_in[5];
    const float* Wk  = (const float*)d_in[6];
    const float* bk  = (const float*)d_in[7];
    const float* Wv  = (const float*)d_in[8];
    const float* bv  = (const float*)d_in[9];
    const float* Ws  = (const float*)d_in[10];
    const float* bs  = (const float*)d_in[11];
    float* out = (float*)d_out;

    char* ws = (char*)d_ws;
    int* cnt4   = (int*)(ws + 0);
    int* cursor = (int*)(ws + 800000);
    int* ebuf   = (int*)(ws + 1000000);
    __hip_bfloat16* x2  = (__hip_bfloat16*)(ws + 26600000);
    __hip_bfloat16* qkv = (__hip_bfloat16*)(ws + 52200000);
    __hip_bfloat16* WT  = (__hip_bfloat16*)(ws + 129000000);
    float* bias = (float*)(ws + 129524288);

    hipMemsetAsync(ws, 0, 1000000, stream);   // cnt4 + cursor
    prep_wt<<<128, 256, 0, stream>>>(Wq, bq, Wk, bk, Wv, bv, Ws, bs, WT, bias);
    count_scatter<<<(N_EDGES + 255) / 256, 256, 0, stream>>>(ei, et, cnt4, cursor, ebuf);
    node_feat<<<N_NODES, 256, 0, stream>>>(x, emb, cnt4, x2);
    gemm_qkvs<<<dim3((N_NODES + 127) / 128, 8), 256, 0, stream>>>(x2, WT, bias, qkv, out);
    attn<<<(N_NODES * 64) / 256, 256, 0, stream>>>(qkv, cursor, ebuf, out);
}

// Round 2
// 342.041 us; speedup vs baseline: 1.1893x; 1.1893x over previous
//
#include <hip/hip_runtime.h>
#include <hip/hip_bf16.h>

#define N_NODES 50000
#define N_EDGES 800000
#define CAP 128

typedef __attribute__((ext_vector_type(8))) short bf16x8;
typedef __attribute__((ext_vector_type(4))) float f32x4;

__device__ inline float bf2f(short u) {
    unsigned int x = ((unsigned int)(unsigned short)u) << 16;
    return __uint_as_float(x);
}

// ws layout (bytes):
// cnt4:   [N][4] int        @ 0           800000
// cursor: [N] int           @ 800000      200000
// ebuf:   [N][CAP] int      @ 1000000     25600000
// x2:     [N][256] bf16     @ 26600000    25600000
// qkv:    [3][N][256] bf16  @ 52200000    76800000
// WT:     [1024][256] bf16  @ 129000000   524288
// bias:   [1024] f32        @ 129524288   4096

__global__ __launch_bounds__(256) void prep_wt(
    const float* __restrict__ Wq, const float* __restrict__ bq,
    const float* __restrict__ Wk, const float* __restrict__ bk,
    const float* __restrict__ Wv, const float* __restrict__ bv,
    const float* __restrict__ Ws, const float* __restrict__ bs,
    __hip_bfloat16* __restrict__ WT, float* __restrict__ bias)
{
    int tid = blockIdx.x * blockDim.x + threadIdx.x;  // 0..32767
    int ng = tid & 1023;          // output row of WT (n-major over q|k|v|s)
    int kc = tid >> 10;           // 0..31, chunk of 8 k's
    int m = ng >> 8;
    int col = ng & 255;
    const float* W = (m == 0) ? Wq : (m == 1) ? Wk : (m == 2) ? Wv : Ws;
    __align__(16) __hip_bfloat16 tmp[8];
    for (int j = 0; j < 8; ++j)
        tmp[j] = __float2bfloat16(W[(kc * 8 + j) * 256 + col]);
    *(bf16x8*)((ushort*)WT + (size_t)ng * 256 + kc * 8) = *(bf16x8*)tmp;
    if (kc == 0) {
        const float* b = (m == 0) ? bq : (m == 1) ? bk : (m == 2) ? bv : bs;
        bias[ng] = b[col];
    }
}

__global__ __launch_bounds__(256) void count_scatter(
    const int* __restrict__ ei, const int* __restrict__ et,
    int* __restrict__ cnt4, int* __restrict__ cursor, int* __restrict__ ebuf)
{
    int e = blockIdx.x * blockDim.x + threadIdx.x;
    if (e >= N_EDGES) return;
    int s = ei[e];
    int d = ei[N_EDGES + e];
    int t = et[e];
    atomicAdd(&cnt4[s * 4 + t], 1);
    int pos = atomicAdd(&cursor[d], 1);
    if (pos < CAP) ebuf[d * CAP + pos] = s;
}

__global__ __launch_bounds__(256) void node_feat(
    const float* __restrict__ x, const float* __restrict__ emb,
    const int* __restrict__ cnt4, __hip_bfloat16* __restrict__ x2)
{
    int n = blockIdx.x;
    int c = threadIdx.x;
    int c0 = cnt4[n * 4 + 0], c1 = cnt4[n * 4 + 1];
    int c2 = cnt4[n * 4 + 2], c3 = cnt4[n * 4 + 3];
    float cnt = (float)(c0 + c1 + c2 + c3);
    float inv = 1.0f / fmaxf(cnt, 1.0f);
    float v = x[(size_t)n * 256 + c] +
              (c0 * emb[c] + c1 * emb[256 + c] + c2 * emb[512 + c] + c3 * emb[768 + c]) * inv;
    x2[(size_t)n * 256 + c] = __float2bfloat16(v);
}

__global__ __launch_bounds__(256) void gemm_qkvs(
    const __hip_bfloat16* __restrict__ x2, const __hip_bfloat16* __restrict__ WT,
    const float* __restrict__ bias,
    __hip_bfloat16* __restrict__ qkv, float* __restrict__ out)
{
    __shared__ __align__(16) ushort As[128][40];
    __shared__ __align__(16) ushort Bs[128][40];
    int m0 = blockIdx.x * 128;
    int n0 = blockIdx.y * 128;
    int tid = threadIdx.x;
    int lane = tid & 63, w = tid >> 6;
    int wm = w >> 1, wn = w & 1;
    f32x4 acc[4][4] = {};

    const ushort* xp = (const ushort*)x2;
    const ushort* wp = (const ushort*)WT;

    for (int kt = 0; kt < 256; kt += 32) {
        for (int it = 0; it < 2; ++it) {
            int idx = tid + it * 256;            // 0..511
            int row = idx >> 2, ch = (idx & 3) * 8;
            int ar = m0 + row; if (ar >= N_NODES) ar = N_NODES - 1;
            *(bf16x8*)&As[row][ch] = *(const bf16x8*)(xp + (size_t)ar * 256 + kt + ch);
            *(bf16x8*)&Bs[row][ch] = *(const bf16x8*)(wp + (size_t)(n0 + row) * 256 + kt + ch);
        }
        __syncthreads();
        int r = lane & 15, kq = (lane >> 4) * 8;
        bf16x8 af[4], bfr[4];
        for (int mi = 0; mi < 4; ++mi) af[mi]  = *(bf16x8*)&As[wm * 64 + mi * 16 + r][kq];
        for (int ni = 0; ni < 4; ++ni) bfr[ni] = *(bf16x8*)&Bs[wn * 64 + ni * 16 + r][kq];
        for (int mi = 0; mi < 4; ++mi)
            for (int ni = 0; ni < 4; ++ni)
                acc[mi][ni] = __builtin_amdgcn_mfma_f32_16x16x32_bf16(
                    af[mi], bfr[ni], acc[mi][ni], 0, 0, 0);
        __syncthreads();
    }

    int r = lane & 15, rg = (lane >> 4) * 4;
    int mtx = n0 >> 8;  // 0=q 1=k 2=v 3=s (uniform per block since BN=128)
    for (int mi = 0; mi < 4; ++mi) {
        int rowb = m0 + wm * 64 + mi * 16 + rg;
        for (int ni = 0; ni < 4; ++ni) {
            int gcol = n0 + wn * 64 + ni * 16 + r;
            float b = bias[gcol];
            int col = gcol & 255;
            for (int rr = 0; rr < 4; ++rr) {
                int row = rowb + rr;
                if (row < N_NODES) {
                    float v = acc[mi][ni][rr] + b;
                    if (mtx == 3) out[(size_t)row * 256 + col] = v;
                    else ((__hip_bfloat16*)qkv)[(size_t)mtx * N_NODES * 256 +
                                                (size_t)row * 256 + col] = __float2bfloat16(v);
                }
            }
        }
    }
}

// One wave per node; 4 edges processed concurrently (16 lanes per edge).
// Lane (g=lane>>4, li=lane&15) owns channels [16*li, 16*li+16) of the
// concatenated 256-channel space; its head is li>>2. Each group g keeps an
// independent online-softmax partial over edges {g, g+4, ...}; partials are
// merged with a 2-step xor butterfly (d=16,32) at the end.
__global__ __launch_bounds__(256) void attn(
    const __hip_bfloat16* __restrict__ qkv,
    const int* __restrict__ cursor, const int* __restrict__ ebuf,
    float* __restrict__ out)
{
    int wid = (blockIdx.x * blockDim.x + threadIdx.x) >> 6;
    int lane = threadIdx.x & 63;
    if (wid >= N_NODES) return;
    int n = wid;
    int g = lane >> 4;
    int li = lane & 15;
    const ushort* qb = (const ushort*)qkv;
    const ushort* kb = qb + (size_t)N_NODES * 256;
    const ushort* vb = qb + (size_t)2 * N_NODES * 256;

    float qf[16];
    {
        bf16x8 q0 = *(const bf16x8*)(qb + (size_t)n * 256 + li * 16);
        bf16x8 q1 = *(const bf16x8*)(qb + (size_t)n * 256 + li * 16 + 8);
        for (int j = 0; j < 8; ++j) { qf[j] = bf2f(q0[j]); qf[8 + j] = bf2f(q1[j]); }
    }

    int deg = cursor[n]; if (deg > CAP) deg = CAP;
    int s0 = 0, s1 = 0;
    if (lane < deg) s0 = ebuf[n * CAP + lane];
    if (lane + 64 < deg) s1 = ebuf[n * CAP + 64 + lane];

    float m = -1e30f, lsum = 0.0f;
    float acc[16];
    for (int j = 0; j < 16; ++j) acc[j] = 0.0f;

    int nit = (deg + 3) >> 2;
    for (int it = 0; it < nit; ++it) {
        int idx = it * 4 + g;
        bool valid = idx < deg;
        int eidx = valid ? idx : 0;
        int a = __shfl(s0, eidx & 63);
        int b = __shfl(s1, eidx & 63);
        int src = (eidx < 64) ? a : b;

        const ushort* kr = kb + (size_t)src * 256 + li * 16;
        const ushort* vr = vb + (size_t)src * 256 + li * 16;
        bf16x8 k0 = *(const bf16x8*)kr;
        bf16x8 k1 = *(const bf16x8*)(kr + 8);
        bf16x8 v0 = *(const bf16x8*)vr;
        bf16x8 v1 = *(const bf16x8*)(vr + 8);

        float p = 0.0f;
        for (int j = 0; j < 8; ++j) p += qf[j] * bf2f(k0[j]);
        for (int j = 0; j < 8; ++j) p += qf[8 + j] * bf2f(k1[j]);
        p += __shfl_xor(p, 1);
        p += __shfl_xor(p, 2);

        float alpha = valid ? p * 0.125f : -1e30f;   // 1/sqrt(64)
        float mn = fmaxf(m, alpha);
        float sc = __expf(m - mn);
        float wgt = valid ? __expf(alpha - mn) : 0.0f;
        lsum = lsum * sc + wgt;
        m = mn;
        for (int j = 0; j < 8; ++j) acc[j]     = acc[j]     * sc + wgt * bf2f(v0[j]);
        for (int j = 0; j < 8; ++j) acc[8 + j] = acc[8 + j] * sc + wgt * bf2f(v1[j]);
    }

    // merge the 4 per-group partials
    for (int d = 16; d <= 32; d <<= 1) {
        float m2 = __shfl_xor(m, d);
        float l2 = __shfl_xor(lsum, d);
        float mn = fmaxf(m, m2);
        float f1 = __expf(m - mn);
        float f2 = __expf(m2 - mn);
        lsum = lsum * f1 + l2 * f2;
        for (int j = 0; j < 16; ++j)
            acc[j] = acc[j] * f1 + __shfl_xor(acc[j], d) * f2;
        m = mn;
    }

    float inv = 1.0f / (lsum + 1e-16f);
    // lane (g,li) writes channels li*16 + g*4 .. +3 (all lanes hold merged acc)
    float* op = out + (size_t)n * 256 + li * 16 + g * 4;
    f32x4 cur = *(f32x4*)op;
    for (int j = 0; j < 4; ++j) cur[j] += acc[g * 4 + j] * inv;
    *(f32x4*)op = cur;
}

extern "C" void kernel_launch(void* const* d_in, const int* in_sizes, int n_in,
                              void* d_out, int out_size, void* d_ws, size_t ws_size,
                              hipStream_t stream)
{
    const float* x   = (const float*)d_in[0];
    const int*   ei  = (const int*)d_in[1];
    const int*   et  = (const int*)d_in[2];
    const float* emb = (const float*)d_in[3];
    const float* Wq  = (const float*)d_in[4];
    const float* bq  = (const float*)d_in[5];
    const float* Wk  = (const float*)d_in[6];
    const float* bk  = (const float*)d_in[7];
    const float* Wv  = (const float*)d_in[8];
    const float* bv  = (const float*)d_in[9];
    const float* Ws  = (const float*)d_in[10];
    const float* bs  = (const float*)d_in[11];
    float* out = (float*)d_out;

    char* ws = (char*)d_ws;
    int* cnt4   = (int*)(ws + 0);
    int* cursor = (int*)(ws + 800000);
    int* ebuf   = (int*)(ws + 1000000);
    __hip_bfloat16* x2  = (__hip_bfloat16*)(ws + 26600000);
    __hip_bfloat16* qkv = (__hip_bfloat16*)(ws + 52200000);
    __hip_bfloat16* WT  = (__hip_bfloat16*)(ws + 129000000);
    float* bias = (float*)(ws + 129524288);

    hipMemsetAsync(ws, 0, 1000000, stream);   // cnt4 + cursor
    prep_wt<<<128, 256, 0, stream>>>(Wq, bq, Wk, bk, Wv, bv, Ws, bs, WT, bias);
    count_scatter<<<(N_EDGES + 255) / 256, 256, 0, stream>>>(ei, et, cnt4, cursor, ebuf);
    node_feat<<<N_NODES, 256, 0, stream>>>(x, emb, cnt4, x2);
    gemm_qkvs<<<dim3((N_NODES + 127) / 128, 8), 256, 0, stream>>>(x2, WT, bias, qkv, out);
    attn<<<(N_NODES * 64) / 256, 256, 0, stream>>>(qkv, cursor, ebuf, out);
}

// Round 3
// 340.956 us; speedup vs baseline: 1.1931x; 1.0032x over previous
//
#include <hip/hip_runtime.h>
#include <hip/hip_bf16.h>

#define N_NODES 50000
#define N_EDGES 800000
#define CAP 128

typedef __attribute__((ext_vector_type(8))) short bf16x8;
typedef __attribute__((ext_vector_type(4))) float f32x4;

__device__ inline float bf2f(short u) {
    unsigned int x = ((unsigned int)(unsigned short)u) << 16;
    return __uint_as_float(x);
}

// ws layout (bytes):
// cnt4:   [N][4] int        @ 0           800000
// cursor: [N] int           @ 800000      200000
// ebuf:   [N][CAP] int      @ 1000000     25600000
// x2:     [N][256] bf16     @ 26600000    25600000
// qkv:    [3][N][256] bf16  @ 52200000    76800000
// WT:     [1024][256] bf16  @ 129000000   524288
// bias:   [1024] f32        @ 129524288   4096

__global__ __launch_bounds__(256) void prep_wt(
    const float* __restrict__ Wq, const float* __restrict__ bq,
    const float* __restrict__ Wk, const float* __restrict__ bk,
    const float* __restrict__ Wv, const float* __restrict__ bv,
    const float* __restrict__ Ws, const float* __restrict__ bs,
    __hip_bfloat16* __restrict__ WT, float* __restrict__ bias)
{
    int tid = blockIdx.x * blockDim.x + threadIdx.x;  // 0..32767
    int ng = tid & 1023;          // output row of WT (n-major over q|k|v|s)
    int kc = tid >> 10;           // 0..31, chunk of 8 k's
    int m = ng >> 8;
    int col = ng & 255;
    const float* W = (m == 0) ? Wq : (m == 1) ? Wk : (m == 2) ? Wv : Ws;
    __align__(16) __hip_bfloat16 tmp[8];
    for (int j = 0; j < 8; ++j)
        tmp[j] = __float2bfloat16(W[(kc * 8 + j) * 256 + col]);
    *(bf16x8*)((ushort*)WT + (size_t)ng * 256 + kc * 8) = *(bf16x8*)tmp;
    if (kc == 0) {
        const float* b = (m == 0) ? bq : (m == 1) ? bk : (m == 2) ? bv : bs;
        bias[ng] = b[col];
    }
}

__global__ __launch_bounds__(256) void count_scatter(
    const int* __restrict__ ei, const int* __restrict__ et,
    int* __restrict__ cnt4, int* __restrict__ cursor, int* __restrict__ ebuf)
{
    int e = blockIdx.x * blockDim.x + threadIdx.x;
    if (e >= N_EDGES) return;
    int s = ei[e];
    int d = ei[N_EDGES + e];
    int t = et[e];
    atomicAdd(&cnt4[s * 4 + t], 1);
    int pos = atomicAdd(&cursor[d], 1);
    if (pos < CAP) ebuf[d * CAP + pos] = s;
}

__global__ __launch_bounds__(256) void node_feat(
    const float* __restrict__ x, const float* __restrict__ emb,
    const int* __restrict__ cnt4, __hip_bfloat16* __restrict__ x2)
{
    int n = blockIdx.x;
    int c = threadIdx.x;
    int c0 = cnt4[n * 4 + 0], c1 = cnt4[n * 4 + 1];
    int c2 = cnt4[n * 4 + 2], c3 = cnt4[n * 4 + 3];
    float cnt = (float)(c0 + c1 + c2 + c3);
    float inv = 1.0f / fmaxf(cnt, 1.0f);
    float v = x[(size_t)n * 256 + c] +
              (c0 * emb[c] + c1 * emb[256 + c] + c2 * emb[512 + c] + c3 * emb[768 + c]) * inv;
    x2[(size_t)n * 256 + c] = __float2bfloat16(v);
}

__global__ __launch_bounds__(256) void gemm_qkvs(
    const __hip_bfloat16* __restrict__ x2, const __hip_bfloat16* __restrict__ WT,
    const float* __restrict__ bias,
    __hip_bfloat16* __restrict__ qkv, float* __restrict__ out)
{
    __shared__ __align__(16) ushort As[128][40];
    __shared__ __align__(16) ushort Bs[128][40];
    int m0 = blockIdx.x * 128;
    int n0 = blockIdx.y * 128;
    int tid = threadIdx.x;
    int lane = tid & 63, w = tid >> 6;
    int wm = w >> 1, wn = w & 1;
    f32x4 acc[4][4] = {};

    const ushort* xp = (const ushort*)x2;
    const ushort* wp = (const ushort*)WT;

    for (int kt = 0; kt < 256; kt += 32) {
        for (int it = 0; it < 2; ++it) {
            int idx = tid + it * 256;            // 0..511
            int row = idx >> 2, ch = (idx & 3) * 8;
            int ar = m0 + row; if (ar >= N_NODES) ar = N_NODES - 1;
            *(bf16x8*)&As[row][ch] = *(const bf16x8*)(xp + (size_t)ar * 256 + kt + ch);
            *(bf16x8*)&Bs[row][ch] = *(const bf16x8*)(wp + (size_t)(n0 + row) * 256 + kt + ch);
        }
        __syncthreads();
        int r = lane & 15, kq = (lane >> 4) * 8;
        bf16x8 af[4], bfr[4];
        for (int mi = 0; mi < 4; ++mi) af[mi]  = *(bf16x8*)&As[wm * 64 + mi * 16 + r][kq];
        for (int ni = 0; ni < 4; ++ni) bfr[ni] = *(bf16x8*)&Bs[wn * 64 + ni * 16 + r][kq];
        for (int mi = 0; mi < 4; ++mi)
            for (int ni = 0; ni < 4; ++ni)
                acc[mi][ni] = __builtin_amdgcn_mfma_f32_16x16x32_bf16(
                    af[mi], bfr[ni], acc[mi][ni], 0, 0, 0);
        __syncthreads();
    }

    int r = lane & 15, rg = (lane >> 4) * 4;
    int mtx = n0 >> 8;  // 0=q 1=k 2=v 3=s (uniform per block since BN=128)
    for (int mi = 0; mi < 4; ++mi) {
        int rowb = m0 + wm * 64 + mi * 16 + rg;
        for (int ni = 0; ni < 4; ++ni) {
            int gcol = n0 + wn * 64 + ni * 16 + r;
            float b = bias[gcol];
            int col = gcol & 255;
            for (int rr = 0; rr < 4; ++rr) {
                int row = rowb + rr;
                if (row < N_NODES) {
                    float v = acc[mi][ni][rr] + b;
                    if (mtx == 3) out[(size_t)row * 256 + col] = v;
                    else ((__hip_bfloat16*)qkv)[(size_t)mtx * N_NODES * 256 +
                                                (size_t)row * 256 + col] = __float2bfloat16(v);
                }
            }
        }
    }
}

// One wave per node; 4 edges processed concurrently (16 lanes per edge).
// Lane (g=lane>>4, li=lane&15) owns channels [16*li, 16*li+16); head = li>>2.
// 1-deep software pipeline: iteration it issues the gathers for it+1 before
// consuming it's registers, hiding L2/L3 gather latency under the compute.
__global__ __launch_bounds__(256) void attn(
    const __hip_bfloat16* __restrict__ qkv,
    const int* __restrict__ cursor, const int* __restrict__ ebuf,
    float* __restrict__ out)
{
    int wid = (blockIdx.x * blockDim.x + threadIdx.x) >> 6;
    int lane = threadIdx.x & 63;
    if (wid >= N_NODES) return;
    int n = wid;
    int g = lane >> 4;
    int li = lane & 15;
    const ushort* qb = (const ushort*)qkv;
    const ushort* kb = qb + (size_t)N_NODES * 256;
    const ushort* vb = qb + (size_t)2 * N_NODES * 256;

    // prologue: hoist the skip-connection RMW read so it overlaps the loop
    float* op = out + (size_t)n * 256 + li * 16 + g * 4;
    f32x4 cur = *(f32x4*)op;

    float qf[16];
    {
        bf16x8 q0 = *(const bf16x8*)(qb + (size_t)n * 256 + li * 16);
        bf16x8 q1 = *(const bf16x8*)(qb + (size_t)n * 256 + li * 16 + 8);
        for (int j = 0; j < 8; ++j) { qf[j] = bf2f(q0[j]); qf[8 + j] = bf2f(q1[j]); }
    }

    int deg = cursor[n]; if (deg > CAP) deg = CAP;
    int s0 = 0, s1 = 0;
    if (lane < deg) s0 = ebuf[n * CAP + lane];
    if (lane + 64 < deg) s1 = ebuf[n * CAP + 64 + lane];

    float m = -1e30f, lsum = 0.0f;
    float acc[16];
    for (int j = 0; j < 16; ++j) acc[j] = 0.0f;

    int nit = (deg + 3) >> 2;
    if (nit > 0) {
        // load iteration 0
        bool valid_c = g < deg;
        int src_c = __shfl(s0, g);        // idx<4 -> always in s0
        const ushort* kr = kb + (size_t)src_c * 256 + li * 16;
        const ushort* vr = vb + (size_t)src_c * 256 + li * 16;
        bf16x8 k0 = *(const bf16x8*)kr;
        bf16x8 k1 = *(const bf16x8*)(kr + 8);
        bf16x8 v0 = *(const bf16x8*)vr;
        bf16x8 v1 = *(const bf16x8*)(vr + 8);

        for (int it = 0; it < nit; ++it) {
            // ---- prefetch it+1 ----
            bool valid_n = false;
            int src_n = 0;
            if (it + 1 < nit) {
                int idx = (it + 1) * 4 + g;
                valid_n = idx < deg;
                int eidx = valid_n ? idx : 0;
                int aa = __shfl(s0, eidx & 63);
                int bb = __shfl(s1, eidx & 63);
                src_n = (eidx < 64) ? aa : bb;
            }
            const ushort* krn = kb + (size_t)src_n * 256 + li * 16;
            const ushort* vrn = vb + (size_t)src_n * 256 + li * 16;
            bf16x8 nk0 = *(const bf16x8*)krn;
            bf16x8 nk1 = *(const bf16x8*)(krn + 8);
            bf16x8 nv0 = *(const bf16x8*)vrn;
            bf16x8 nv1 = *(const bf16x8*)(vrn + 8);

            // ---- consume current ----
            float p = 0.0f;
            for (int j = 0; j < 8; ++j) p += qf[j] * bf2f(k0[j]);
            for (int j = 0; j < 8; ++j) p += qf[8 + j] * bf2f(k1[j]);
            p += __shfl_xor(p, 1);
            p += __shfl_xor(p, 2);

            float alpha = valid_c ? p * 0.125f : -1e30f;   // 1/sqrt(64)
            float mn = fmaxf(m, alpha);
            float sc = __expf(m - mn);
            float wgt = valid_c ? __expf(alpha - mn) : 0.0f;
            lsum = lsum * sc + wgt;
            m = mn;
            for (int j = 0; j < 8; ++j) acc[j]     = acc[j]     * sc + wgt * bf2f(v0[j]);
            for (int j = 0; j < 8; ++j) acc[8 + j] = acc[8 + j] * sc + wgt * bf2f(v1[j]);

            // ---- rotate ----
            k0 = nk0; k1 = nk1; v0 = nv0; v1 = nv1;
            valid_c = valid_n;
        }
    }

    // merge the 4 per-group partials
    for (int d = 16; d <= 32; d <<= 1) {
        float m2 = __shfl_xor(m, d);
        float l2 = __shfl_xor(lsum, d);
        float mn = fmaxf(m, m2);
        float f1 = __expf(m - mn);
        float f2 = __expf(m2 - mn);
        lsum = lsum * f1 + l2 * f2;
        for (int j = 0; j < 16; ++j)
            acc[j] = acc[j] * f1 + __shfl_xor(acc[j], d) * f2;
        m = mn;
    }

    float inv = 1.0f / (lsum + 1e-16f);
    // lane (g,li) writes channels li*16 + g*4 .. +3 (all lanes hold merged acc)
    for (int j = 0; j < 4; ++j) cur[j] += acc[g * 4 + j] * inv;
    *(f32x4*)op = cur;
}

extern "C" void kernel_launch(void* const* d_in, const int* in_sizes, int n_in,
                              void* d_out, int out_size, void* d_ws, size_t ws_size,
                              hipStream_t stream)
{
    const float* x   = (const float*)d_in[0];
    const int*   ei  = (const int*)d_in[1];
    const int*   et  = (const int*)d_in[2];
    const float* emb = (const float*)d_in[3];
    const float* Wq  = (const float*)d_in[4];
    const float* bq  = (const float*)d_in[5];
    const float* Wk  = (const float*)d_in[6];
    const float* bk  = (const float*)d_in[7];
    const float* Wv  = (const float*)d_in[8];
    const float* bv  = (const float*)d_in[9];
    const float* Ws  = (const float*)d_in[10];
    const float* bs  = (const float*)d_in[11];
    float* out = (float*)d_out;

    char* ws = (char*)d_ws;
    int* cnt4   = (int*)(ws + 0);
    int* cursor = (int*)(ws + 800000);
    int* ebuf   = (int*)(ws + 1000000);
    __hip_bfloat16* x2  = (__hip_bfloat16*)(ws + 26600000);
    __hip_bfloat16* qkv = (__hip_bfloat16*)(ws + 52200000);
    __hip_bfloat16* WT  = (__hip_bfloat16*)(ws + 129000000);
    float* bias = (float*)(ws + 129524288);

    hipMemsetAsync(ws, 0, 1000000, stream);   // cnt4 + cursor
    prep_wt<<<128, 256, 0, stream>>>(Wq, bq, Wk, bk, Wv, bv, Ws, bs, WT, bias);
    count_scatter<<<(N_EDGES + 255) / 256, 256, 0, stream>>>(ei, et, cnt4, cursor, ebuf);
    node_feat<<<N_NODES, 256, 0, stream>>>(x, emb, cnt4, x2);
    gemm_qkvs<<<dim3((N_NODES + 127) / 128, 8), 256, 0, stream>>>(x2, WT, bias, qkv, out);
    attn<<<(N_NODES * 64) / 256, 256, 0, stream>>>(qkv, cursor, ebuf, out);
}